// Round 10
// baseline (386.040 us; speedup 1.0000x reference)
//
#include <hip/hip_runtime.h>

#define N_SEQ 16384
#define LSEQ  512
#define VOCAB 32000
#define ES    32
#define HS    64
#define LDH   72    // padded f16 stride per m-row in LDS

#define SC_RZ (-1.4426950408889634f)   // -log2(e): folded into r,z weights
#define SC_N  (-2.8853900817779268f)   // -2*log2(e): folded into n weights

typedef _Float16 v8h __attribute__((ext_vector_type(8)));
typedef float    v4f __attribute__((ext_vector_type(4)));

// ---------------- K1 (fused prep): lengths+hist | emb->f16 | weight packs ---
#define NLB (N_SEQ / 4)            // 4096 blocks: lengths
#define NEB (VOCAB * ES / 256)     // 4000 blocks: emb convert
__global__ __launch_bounds__(256) void k_prep(const int* __restrict__ x,
                                              const float* __restrict__ emb,
                                              const float* __restrict__ whh,
                                              const float* __restrict__ wih,
                                              int* __restrict__ len,
                                              int* __restrict__ hist,
                                              _Float16* __restrict__ ef,
                                              _Float16* __restrict__ wpk,
                                              _Float16* __restrict__ wpe){
  int b = blockIdx.x;
  if (b < NLB){                               // ---- lengths + histogram
    int wid  = (b * 256 + threadIdx.x) >> 6;
    int lane = threadIdx.x & 63;
    const int* xr = x + (size_t)wid * LSEQ;
    int cnt = 0;
    #pragma unroll
    for (int j = 0; j < 8; ++j) cnt += (xr[lane + 64*j] != 0) ? 1 : 0;
    #pragma unroll
    for (int o = 32; o; o >>= 1) cnt += __shfl_down(cnt, o, 64);
    if (lane == 0){ len[wid] = cnt; atomicAdd(&hist[cnt], 1); }
  } else if (b < NLB + NEB){                  // ---- embedding f32 -> f16
    int i = (b - NLB) * 256 + threadIdx.x;
    ef[i] = (_Float16)emb[i];
  } else if (b < NLB + NEB + 6){              // ---- pack w_hh (K=64: 2 frags)
    int tid = (b - NLB - NEB) * 256 + threadIdx.x;
    int f = tid >> 6, l = tid & 63;
    int jt = f >> 1, kf = f & 1;
    float sc = (jt < 8) ? SC_RZ : SC_N;       // exp2-arg scale folded in
    #pragma unroll
    for (int i = 0; i < 8; ++i){
      int row = jt * 16 + (l & 15);
      int col = kf * 32 + (l >> 4) * 8 + i;
      wpk[(size_t)tid * 8 + i] = (_Float16)(sc * whh[row * HS + col]);
    }
  } else {                                    // ---- pack w_ih (K=32: 1 frag)
    int tid = (b - NLB - NEB - 6) * 256 + threadIdx.x;
    int tile = tid >> 6, l = tid & 63;
    float sc = ((tile >> 2) < 2) ? SC_RZ : SC_N;
    #pragma unroll
    for (int i = 0; i < 8; ++i){
      int row = tile * 16 + (l & 15);
      int col = (l >> 4) * 8 + i;
      wpe[(size_t)tid * 8 + i] = (_Float16)(sc * wih[row * ES + col]);
    }
  }
}

// ---------------- K2: exclusive scan of hist[0..512] -> offs ----------------
__global__ __launch_bounds__(1024) void k_scan(const int* __restrict__ hist,
                                               int* __restrict__ offs){
  __shared__ int buf[1024];
  int i = threadIdx.x;
  buf[i] = (i < 513) ? hist[i] : 0;
  __syncthreads();
  for (int d = 1; d < 1024; d <<= 1){
    int v = (i >= d) ? buf[i - d] : 0;
    __syncthreads();
    buf[i] += v;
    __syncthreads();
  }
  if (i < 513) offs[i] = (i == 0) ? 0 : buf[i - 1];
}

// ---------------- K3: scatter seq ids sorted (ascending) by length ----------
__global__ __launch_bounds__(256) void k_scatter(const int* __restrict__ len,
                                                 int* __restrict__ offs,
                                                 int* __restrict__ perm){
  int i = blockIdx.x * 256 + threadIdx.x;
  int l = len[i];
  int pos = atomicAdd(&offs[l], 1);
  perm[pos] = i;
}

// ---------------- K4: recurrence, dual-group blocks -------------------------
// Each 4-wave block runs TWO adjacent sorted groups (32 seqs): two independent
// recurrence chains interleaved at instruction level inside every wave (ILP the
// scheduler can't miss), one barrier + one loop-control per dual-step, B-frags
// shared. 512 blocks -> 2/CU; serpentine pairing keeps per-CU work equal.
// e-accs single-buffered: computed at step start from the prefetched emb frag
// (independent of the LDS h path, MFMA latency hidden by the ds_read wait).
__global__ __launch_bounds__(256, 2) void k_gru(
    const int* __restrict__ x, const _Float16* __restrict__ ef,
    const _Float16* __restrict__ wpk, const _Float16* __restrict__ wpe,
    const float* __restrict__ bih, const float* __restrict__ bhh,
    const int* __restrict__ perm, const int* __restrict__ len,
    float* __restrict__ out)
{
  __shared__ __align__(16) _Float16 hb[2][2][16 * LDH];   // [group][pingpong]
  int qt   = threadIdx.x >> 6;
  int w = blockIdx.x >> 8, cq = blockIdx.x & 255;         // 512 blocks
  int rank = w * 256 + ((w & 1) ? (255 - cq) : cq);       // 0 = longest pair
  int pr   = 511 - rank;                                  // ascending pair idx
  int gA = pr * 2, gB = pr * 2 + 1;
  int lane = threadIdx.x & 63;
  int q = lane >> 4, c = lane & 15;
  int uu = qt*16 + c;

  v8h bfh[3][2], bfe[3];
  #pragma unroll
  for (int g = 0; g < 3; ++g){
    int tile = g*4 + qt;
    #pragma unroll
    for (int kf = 0; kf < 2; ++kf)
      bfh[g][kf] = *(const v8h*)(wpk + ((size_t)(tile*2 + kf)*64 + lane)*8);
    bfe[g] = *(const v8h*)(wpe + ((size_t)tile*64 + lane)*8);
  }

  int sqA[4], lnA[4], sqB[4], lnB[4];
  #pragma unroll
  for (int r = 0; r < 4; ++r){
    int sA = perm[gA * 16 + q*4 + r];  sqA[r] = sA;  lnA[r] = len[sA];
    int sB = perm[gB * 16 + q*4 + r];  sqB[r] = sB;  lnB[r] = len[sB];
  }
  float br  = SC_RZ * (bih[uu]      + bhh[uu]);
  float bz  = SC_RZ * (bih[HS + uu] + bhh[HS + uu]);
  float ben = SC_N  *  bih[2*HS + uu];
  float bhn = SC_N  *  bhh[2*HS + uu];
  v4f brq  = {br, br, br, br};
  v4f bzq  = {bz, bz, bz, bz};
  v4f benq = {ben, ben, ben, ben};
  v4f bhnq = {bhn, bhn, bhn, bhn};

  float hA[4], hB[4];
  #pragma unroll
  for (int r = 0; r < 4; ++r){ hA[r] = 0.f; hB[r] = 0.f; }

  for (int i = threadIdx.x; i < 16*LDH; i += 256){
    hb[0][0][i] = (_Float16)0.f;
    hb[1][0][i] = (_Float16)0.f;
  }
  __syncthreads();

  int tmax = max(max(lnA[0], lnA[1]), max(lnA[2], lnA[3]));
  tmax = max(tmax, max(max(lnB[0], lnB[1]), max(lnB[2], lnB[3])));
  tmax = max(tmax, __shfl_xor(tmax, 16, 64));
  tmax = max(tmax, __shfl_xor(tmax, 32, 64));
  int tmin = min(min(lnA[0], lnA[1]), min(lnA[2], lnA[3]));
  tmin = min(tmin, min(min(lnB[0], lnB[1]), min(lnB[2], lnB[3])));
  tmin = min(tmin, __shfl_xor(tmin, 16, 64));
  tmin = min(tmin, __shfl_xor(tmin, 32, 64));

  const int* xrA = x + (size_t)perm[gA * 16 + c] * LSEQ;  // A-row m=c tokens
  const int* xrB = x + (size_t)perm[gB * 16 + c] * LSEQ;

  v8h aecA, aenA, aecB, aenB;
  int tkA1, tkA2, tkB1, tkB2;
  {
    aecA = *(const v8h*)(ef + (size_t)xrA[0] * ES + q*8);
    aecB = *(const v8h*)(ef + (size_t)xrB[0] * ES + q*8);
    tkA1 = xrA[1];  tkB1 = xrB[1];
  }

  #define LDS_BARRIER() __asm__ volatile("s_waitcnt lgkmcnt(0)\n\ts_barrier" ::: "memory")

  #define DUAL_STEP(FREEZE, AECA, AENA, TKA1_, TKA2_, AECB, AENB, TKB1_, TKB2_, RB, WB) \
  {                                                                            \
    AENA = *(const v8h*)(ef + (size_t)TKA1_ * ES + q*8);                       \
    AENB = *(const v8h*)(ef + (size_t)TKB1_ * ES + q*8);                       \
    int t2 = min(t + 2, LSEQ - 1);                                             \
    TKA2_ = xrA[t2];  TKB2_ = xrB[t2];                                         \
    v4f prA = __builtin_amdgcn_mfma_f32_16x16x32_f16(AECA, bfe[0], brq,  0,0,0);\
    v4f pzA = __builtin_amdgcn_mfma_f32_16x16x32_f16(AECA, bfe[1], bzq,  0,0,0);\
    v4f deA = __builtin_amdgcn_mfma_f32_16x16x32_f16(AECA, bfe[2], benq, 0,0,0);\
    v4f prB = __builtin_amdgcn_mfma_f32_16x16x32_f16(AECB, bfe[0], brq,  0,0,0);\
    v4f pzB = __builtin_amdgcn_mfma_f32_16x16x32_f16(AECB, bfe[1], bzq,  0,0,0);\
    v4f deB = __builtin_amdgcn_mfma_f32_16x16x32_f16(AECB, bfe[2], benq, 0,0,0);\
    v8h a0A = *(const v8h*)(&hb[0][RB][c*LDH + q*8]);                          \
    v8h a1A = *(const v8h*)(&hb[0][RB][c*LDH + 32 + q*8]);                     \
    v8h a0B = *(const v8h*)(&hb[1][RB][c*LDH + q*8]);                          \
    v8h a1B = *(const v8h*)(&hb[1][RB][c*LDH + 32 + q*8]);                     \
    v4f zrA  = __builtin_amdgcn_mfma_f32_16x16x32_f16(a1A, bfh[0][1], prA, 0,0,0);\
    v4f DrA  = __builtin_amdgcn_mfma_f32_16x16x32_f16(a0A, bfh[0][0], zrA, 0,0,0);\
    v4f zzA  = __builtin_amdgcn_mfma_f32_16x16x32_f16(a1A, bfh[1][1], pzA, 0,0,0);\
    v4f DzA  = __builtin_amdgcn_mfma_f32_16x16x32_f16(a0A, bfh[1][0], zzA, 0,0,0);\
    v4f zhA  = __builtin_amdgcn_mfma_f32_16x16x32_f16(a1A, bfh[2][1], bhnq,0,0,0);\
    v4f DhnA = __builtin_amdgcn_mfma_f32_16x16x32_f16(a0A, bfh[2][0], zhA, 0,0,0);\
    v4f zrB  = __builtin_amdgcn_mfma_f32_16x16x32_f16(a1B, bfh[0][1], prB, 0,0,0);\
    v4f DrB  = __builtin_amdgcn_mfma_f32_16x16x32_f16(a0B, bfh[0][0], zrB, 0,0,0);\
    v4f zzB  = __builtin_amdgcn_mfma_f32_16x16x32_f16(a1B, bfh[1][1], pzB, 0,0,0);\
    v4f DzB  = __builtin_amdgcn_mfma_f32_16x16x32_f16(a0B, bfh[1][0], zzB, 0,0,0);\
    v4f zhB  = __builtin_amdgcn_mfma_f32_16x16x32_f16(a1B, bfh[2][1], bhnq,0,0,0);\
    v4f DhnB = __builtin_amdgcn_mfma_f32_16x16x32_f16(a0B, bfh[2][0], zhB, 0,0,0);\
    _Pragma("unroll")                                                          \
    for (int r = 0; r < 4; ++r){                                               \
      float rgA = __builtin_amdgcn_rcpf(1.f + __builtin_amdgcn_exp2f(DrA[r])); \
      float zgA = __builtin_amdgcn_rcpf(1.f + __builtin_amdgcn_exp2f(DzA[r])); \
      float teA = __builtin_amdgcn_exp2f(deA[r] + rgA * DhnA[r]);              \
      float ngA = fmaf(2.f, __builtin_amdgcn_rcpf(1.f + teA), -1.f);           \
      float hnA = ngA + zgA * (hA[r] - ngA);                                   \
      hA[r] = (FREEZE && t >= lnA[r]) ? hA[r] : hnA;                           \
      float rgB = __builtin_amdgcn_rcpf(1.f + __builtin_amdgcn_exp2f(DrB[r])); \
      float zgB = __builtin_amdgcn_rcpf(1.f + __builtin_amdgcn_exp2f(DzB[r])); \
      float teB = __builtin_amdgcn_exp2f(deB[r] + rgB * DhnB[r]);              \
      float ngB = fmaf(2.f, __builtin_amdgcn_rcpf(1.f + teB), -1.f);           \
      float hnB = ngB + zgB * (hB[r] - ngB);                                   \
      hB[r] = (FREEZE && t >= lnB[r]) ? hB[r] : hnB;                           \
    }                                                                          \
    _Pragma("unroll")                                                          \
    for (int r = 0; r < 4; ++r){                                               \
      hb[0][WB][(q*4 + r)*LDH + uu] = (_Float16)hA[r];                         \
      hb[1][WB][(q*4 + r)*LDH + uu] = (_Float16)hB[r];                         \
    }                                                                          \
    LDS_BARRIER();                                                             \
  }

  int t = 0;
  for (; t + 1 < tmin; ){   // no-freeze main loop
    DUAL_STEP(0, aecA, aenA, tkA1, tkA2, aecB, aenB, tkB1, tkB2, 0, 1); ++t;
    DUAL_STEP(0, aenA, aecA, tkA2, tkA1, aenB, aecB, tkB2, tkB1, 1, 0); ++t;
  }
  for (; t + 1 < tmax; ){   // tail pairs with freeze
    DUAL_STEP(1, aecA, aenA, tkA1, tkA2, aecB, aenB, tkB1, tkB2, 0, 1); ++t;
    DUAL_STEP(1, aenA, aecA, tkA2, tkA1, aenB, aecB, tkB2, tkB1, 1, 0); ++t;
  }
  if (t < tmax){
    DUAL_STEP(1, aecA, aenA, tkA1, tkA2, aecB, aenB, tkB1, tkB2, 0, 1); ++t;
  }
  #undef DUAL_STEP
  #undef LDS_BARRIER

  #pragma unroll
  for (int r = 0; r < 4; ++r){
    out[(size_t)sqA[r] * HS + uu] = hA[r];
    out[(size_t)sqB[r] * HS + uu] = hB[r];
  }
}

extern "C" void kernel_launch(void* const* d_in, const int* in_sizes, int n_in,
                              void* d_out, int out_size, void* d_ws, size_t ws_size,
                              hipStream_t stream){
  const int*   x   = (const int*)  d_in[0];
  const float* emb = (const float*)d_in[1];
  const float* wih = (const float*)d_in[2];
  const float* whh = (const float*)d_in[3];
  const float* bih = (const float*)d_in[4];
  const float* bhh = (const float*)d_in[5];
  float* out = (float*)d_out;

  char* ws = (char*)d_ws;
  size_t off = 0;
  _Float16* ef  = (_Float16*)(ws + off);  off += (size_t)VOCAB * ES * sizeof(_Float16);
  _Float16* wpk = (_Float16*)(ws + off);  off += (size_t)24 * 64 * 8 * sizeof(_Float16);
  _Float16* wpe = (_Float16*)(ws + off);  off += (size_t)12 * 64 * 8 * sizeof(_Float16);
  off = (off + 255) & ~(size_t)255;
  int* len  = (int*)(ws + off);           off += (size_t)N_SEQ * sizeof(int);
  int* perm = (int*)(ws + off);           off += (size_t)N_SEQ * sizeof(int);
  int* hist = (int*)(ws + off);           off += 513 * sizeof(int);
  off = (off + 255) & ~(size_t)255;
  int* offs = (int*)(ws + off);           off += 513 * sizeof(int);

  hipMemsetAsync(hist, 0, 513 * sizeof(int), stream);
  k_prep   <<<NLB + NEB + 9, 256, 0, stream>>>(x, emb, whh, wih, len, hist, ef, wpk, wpe);
  k_scan   <<<1,            1024, 0, stream>>>(hist, offs);
  k_scatter<<<N_SEQ / 256,   256, 0, stream>>>(len, offs, perm);
  k_gru    <<<N_SEQ / 32,    256, 0, stream>>>(x, ef, wpk, wpe, bih, bhh, perm, len, out);
}